// Round 1
// baseline (1709.807 us; speedup 1.0000x reference)
//
#include <hip/hip_runtime.h>
#include <hip/hip_bf16.h>
#include <cstdint>

#define DEV __device__ __forceinline__

constexpr int Bt = 16384;   // batch
constexpr int Dd = 1024;    // input dim
constexpr int Hh = 4096;    // hidden
constexpr int Cc = 512;     // classes
constexpr int Ee = 8;       // experts
constexpr int PCAP = 33792; // 32768 pairs + 8*128 padding headroom (multiple of 128)

typedef short bf16x8 __attribute__((ext_vector_type(8)));
typedef float f32x4  __attribute__((ext_vector_type(4)));

DEV ushort f2bf(float f){
  uint32_t u = __float_as_uint(f);
  u += 0x7fffu + ((u >> 16) & 1u);
  return (ushort)(u >> 16);
}
DEV float bf2f(ushort u){ return __uint_as_float(((uint32_t)u) << 16); }

typedef const __attribute__((address_space(1))) void* gptr_t;
typedef __attribute__((address_space(3))) void* lptr_t;
DEV void gload_lds16(const void* g, void* l){
  __builtin_amdgcn_global_load_lds((gptr_t)g, (lptr_t)l, 16, 0, 0);
}

// ---------------- router: logits, top-2 softmax, counts ----------------
__global__ __launch_bounds__(256) void k_router(
    const float* __restrict__ x, const float* __restrict__ gw,
    const float* __restrict__ gb, float* __restrict__ logits,
    int2* __restrict__ topi, float2* __restrict__ topp, int* __restrict__ cnt)
{
  __shared__ float lgwT[Ee * Dd];   // gate_w transposed [E][D]
  int tid = threadIdx.x;
  const float4* gw4 = (const float4*)gw;
  for (int i = tid; i < Dd * Ee / 4; i += 256){
    float4 v = gw4[i];
    int d = i >> 1, e0 = (i & 1) * 4;
    lgwT[(e0 + 0) * Dd + d] = v.x;
    lgwT[(e0 + 1) * Dd + d] = v.y;
    lgwT[(e0 + 2) * Dd + d] = v.z;
    lgwT[(e0 + 3) * Dd + d] = v.w;
  }
  __syncthreads();
  int wv = tid >> 6, lane = tid & 63;
  int t = blockIdx.x * 4 + wv;
  const float* xr = x + (size_t)t * Dd;
  float acc[Ee];
  #pragma unroll
  for (int e = 0; e < Ee; e++) acc[e] = 0.f;
  for (int i = 0; i < Dd / 64; i++){
    int d = i * 64 + lane;
    float xs = xr[d];
    #pragma unroll
    for (int e = 0; e < Ee; e++) acc[e] += xs * lgwT[e * Dd + d];
  }
  #pragma unroll
  for (int e = 0; e < Ee; e++){
    #pragma unroll
    for (int m = 1; m < 64; m <<= 1) acc[e] += __shfl_xor(acc[e], m, 64);
  }
  if (lane == 0){
    float lg[Ee];
    #pragma unroll
    for (int e = 0; e < Ee; e++) lg[e] = acc[e] + gb[e];
    #pragma unroll
    for (int e = 0; e < Ee; e++) logits[(size_t)t * Ee + e] = lg[e];
    // top-2, lowest index wins ties (matches jax.lax.top_k)
    int i0 = 0; float v0 = lg[0];
    #pragma unroll
    for (int e = 1; e < Ee; e++) if (lg[e] > v0){ v0 = lg[e]; i0 = e; }
    int i1 = (i0 == 0) ? 1 : 0; float v1 = lg[i1];
    #pragma unroll
    for (int e = 0; e < Ee; e++) if (e != i0 && lg[e] > v1){ v1 = lg[e]; i1 = e; }
    float ex = expf(v1 - v0);
    float p0 = 1.f / (1.f + ex);
    float p1 = ex * p0;
    atomicAdd(&cnt[i0], 1);
    atomicAdd(&cnt[i1], 1);
    topi[t] = make_int2(i0, i1);
    topp[t] = make_float2(p0, p1);
  }
}

// ---------------- padded segment offsets ----------------
__global__ void k_offsets(const int* __restrict__ cnt, int* __restrict__ off)
{
  if (threadIdx.x == 0 && blockIdx.x == 0){
    int a = 0;
    for (int e = 0; e < Ee; e++){ off[e] = a; a += ((cnt[e] + 127) >> 7) << 7; }
    off[Ee] = a;
  }
}

// ---------------- scatter pairs into expert segments ----------------
__global__ __launch_bounds__(256) void k_scatter(
    const int2* __restrict__ topi, const float2* __restrict__ topp,
    const int* __restrict__ off, int* __restrict__ fill,
    int* __restrict__ ptok, float* __restrict__ pgate)
{
  int t = blockIdx.x * 256 + threadIdx.x;
  if (t >= Bt) return;
  int2 ii = topi[t]; float2 pp = topp[t];
  int p0 = off[ii.x] + atomicAdd(&fill[ii.x], 1);
  ptok[p0] = t; pgate[p0] = pp.x;
  int p1 = off[ii.y] + atomicAdd(&fill[ii.y], 1);
  ptok[p1] = t; pgate[p1] = pp.y;
}

// ---------------- fp32 -> bf16 convert ----------------
__global__ __launch_bounds__(256) void k_cvt_bf16(
    const float* __restrict__ in, ushort* __restrict__ outp, int n4)
{
  int i = blockIdx.x * 256 + threadIdx.x;
  if (i >= n4) return;
  float4 v = ((const float4*)in)[i];
  ushort4 o; o.x = f2bf(v.x); o.y = f2bf(v.y); o.z = f2bf(v.z); o.w = f2bf(v.w);
  ((ushort4*)outp)[i] = o;
}

// ---------------- per-expert transpose fp32 [R][Cd] -> bf16 [Cd][R] ----------------
__global__ __launch_bounds__(256) void k_transpose_bf16(
    const float* __restrict__ in, ushort* __restrict__ outp, int R, int Cd)
{
  __shared__ float tl[64][65];
  size_t eoff = (size_t)blockIdx.z * (size_t)R * (size_t)Cd;
  int c0 = blockIdx.x * 64, r0 = blockIdx.y * 64;
  int tid = threadIdx.x;
  int r = tid >> 2, cq = tid & 3;
  const float* src = in + eoff + (size_t)(r0 + r) * Cd + c0 + cq * 16;
  #pragma unroll
  for (int q = 0; q < 4; q++){
    float4 v = ((const float4*)src)[q];
    int cc = cq * 16 + q * 4;
    tl[r][cc + 0] = v.x; tl[r][cc + 1] = v.y; tl[r][cc + 2] = v.z; tl[r][cc + 3] = v.w;
  }
  __syncthreads();
  int c = tid >> 2, rq = tid & 3;
  ushort* dst = outp + eoff + (size_t)(c0 + c) * R + r0 + rq * 16;
  #pragma unroll
  for (int q = 0; q < 4; q++){
    ushort4 o;
    o.x = f2bf(tl[rq * 16 + q * 4 + 0][c]);
    o.y = f2bf(tl[rq * 16 + q * 4 + 1][c]);
    o.z = f2bf(tl[rq * 16 + q * 4 + 2][c]);
    o.w = f2bf(tl[rq * 16 + q * 4 + 3][c]);
    ((ushort4*)dst)[q] = o;
  }
}

// ---------------- grouped GEMM, 128x128 tile, BK=64, bf16 MFMA ----------------
// MODE 0: h_raw = gather(x) @ w1t[e]^T + b1 ; store bf16 h; atomic row sum/sumsq
// MODE 1: out[tok] += gate * (h @ w2t[e]^T + b2)
template<int MODE, int Kd, int Nd>
__global__ __launch_bounds__(256) void k_gemm(
    const ushort* __restrict__ A, const ushort* __restrict__ Bm,
    const float* __restrict__ bias, const int* __restrict__ off,
    const int* __restrict__ ptok, const float* __restrict__ pgate,
    float* __restrict__ stats, ushort* __restrict__ Hout,
    float* __restrict__ Outp, int chunk_base)
{
  __shared__ char lds[32768];  // A tile [128][64] bf16 swizzled | B tile [128][64]
  int tid = threadIdx.x;
  int r0l = blockIdx.x * 128;           // local row base (within chunk)
  int grow0 = chunk_base + r0l;         // global pair row base
  int n0 = blockIdx.y * 128;
  int e = 0;
  #pragma unroll
  for (int i = 1; i < 8; i++) e = (grow0 >= off[i]) ? i : e;

  // staging addresses: chunk = j*256+tid ; row = chunk>>3 ; slot = chunk&7
  int s = tid & 7, rb = tid >> 3;
  uint32_t sx = (uint32_t)((s ^ (rb & 7)) << 4);   // XOR-swizzled 16B slot (T2)
  uint32_t a_src[4], b_src[4];
  #pragma unroll
  for (int j = 0; j < 4; j++){
    int r = rb + j * 32;
    uint32_t rowb;
    if (MODE == 0){ int tok = ptok[grow0 + r]; rowb = (uint32_t)tok * (uint32_t)(Kd * 2); }
    else          { rowb = (uint32_t)(r0l + r) * (uint32_t)(Kd * 2); }
    a_src[j] = rowb + sx;
    b_src[j] = (uint32_t)(e * Nd + n0 + r) * (uint32_t)(Kd * 2) + sx;
  }
  int w = tid >> 6, lane = tid & 63;
  int wm = w >> 1, wn = w & 1;
  int l15 = lane & 15, lhi = lane >> 4, x7 = lane & 7;
  uint32_t aro[4], bro[4];
  #pragma unroll
  for (int mi = 0; mi < 4; mi++) aro[mi] = (uint32_t)((wm * 64 + mi * 16 + l15) * 128);
  #pragma unroll
  for (int ni = 0; ni < 4; ni++) bro[ni] = (uint32_t)(16384 + (wn * 64 + ni * 16 + l15) * 128);

  f32x4 acc[4][4];
  #pragma unroll
  for (int mi = 0; mi < 4; mi++)
    #pragma unroll
    for (int ni = 0; ni < 4; ni++) acc[mi][ni] = (f32x4){0.f, 0.f, 0.f, 0.f};

  const char* Ab = (const char*)A;
  const char* Bb = (const char*)Bm;
  uint32_t ldsA = (uint32_t)(w * 1024);
  uint32_t ldsB = (uint32_t)(16384 + w * 1024);

  for (int kt = 0; kt < Kd / 64; kt++){
    uint32_t koff = (uint32_t)kt * 128u;
    #pragma unroll
    for (int j = 0; j < 4; j++){
      gload_lds16(Ab + a_src[j] + koff, (void*)(lds + ldsA + j * 4096));
      gload_lds16(Bb + b_src[j] + koff, (void*)(lds + ldsB + j * 4096));
    }
    __syncthreads();
    #pragma unroll
    for (int ks = 0; ks < 2; ks++){
      bf16x8 af[4], bfr[4];
      int slot = ks * 4 + lhi;
      uint32_t so = (uint32_t)((slot ^ x7) << 4);
      #pragma unroll
      for (int mi = 0; mi < 4; mi++) af[mi] = *(const bf16x8*)(lds + aro[mi] + so);
      #pragma unroll
      for (int ni = 0; ni < 4; ni++) bfr[ni] = *(const bf16x8*)(lds + bro[ni] + so);
      #pragma unroll
      for (int mi = 0; mi < 4; mi++)
        #pragma unroll
        for (int ni = 0; ni < 4; ni++)
          acc[mi][ni] = __builtin_amdgcn_mfma_f32_16x16x32_bf16(af[mi], bfr[ni], acc[mi][ni], 0, 0, 0);
    }
    __syncthreads();
  }

  // epilogue — C/D map: col = lane&15, row = (lane>>4)*4 + reg
  float bv[4]; int nn[4];
  #pragma unroll
  for (int ni = 0; ni < 4; ni++){
    nn[ni] = n0 + wn * 64 + ni * 16 + l15;
    bv[ni] = bias[e * Nd + nn[ni]];
  }
  if (MODE == 0){
    #pragma unroll
    for (int mi = 0; mi < 4; mi++){
      float s0v[4] = {0, 0, 0, 0}, s1v[4] = {0, 0, 0, 0};
      #pragma unroll
      for (int ni = 0; ni < 4; ni++){
        #pragma unroll
        for (int r = 0; r < 4; r++){
          float v = acc[mi][ni][r] + bv[ni];
          int rl = r0l + wm * 64 + mi * 16 + lhi * 4 + r;
          Hout[(size_t)rl * Nd + nn[ni]] = f2bf(v);
          s0v[r] += v; s1v[r] += v * v;
        }
      }
      #pragma unroll
      for (int r = 0; r < 4; r++){
        float a0 = s0v[r], a1 = s1v[r];
        #pragma unroll
        for (int m = 1; m < 16; m <<= 1){
          a0 += __shfl_xor(a0, m, 64);
          a1 += __shfl_xor(a1, m, 64);
        }
        if (l15 == 0){
          int grow = chunk_base + r0l + wm * 64 + mi * 16 + lhi * 4 + r;
          atomicAdd(&stats[grow * 2 + 0], a0);
          atomicAdd(&stats[grow * 2 + 1], a1);
        }
      }
    }
  } else {
    #pragma unroll
    for (int mi = 0; mi < 4; mi++){
      #pragma unroll
      for (int r = 0; r < 4; r++){
        int rl = r0l + wm * 64 + mi * 16 + lhi * 4 + r;
        int grow = chunk_base + rl;
        int tok = ptok[grow];
        float g = pgate[grow];
        #pragma unroll
        for (int ni = 0; ni < 4; ni++){
          float v = acc[mi][ni][r] + bv[ni];
          atomicAdd(&Outp[(size_t)tok * Nd + nn[ni]], g * v);
        }
      }
    }
  }
}

// ---------------- LayerNorm + exact-erf GELU, in place on bf16 h ----------------
__global__ __launch_bounds__(256) void k_lngelu(
    ushort* __restrict__ h, const float* __restrict__ stats,
    const int* __restrict__ off, const float* __restrict__ lng,
    const float* __restrict__ lnb, int chunk_base)
{
  int gid = blockIdx.x * 256 + threadIdx.x;
  int rl = gid >> 9;             // H/8 = 512 chunks per row
  int c8 = (gid & 511) << 3;
  int grow = chunk_base + rl;
  int e = 0;
  #pragma unroll
  for (int i = 1; i < 8; i++) e = (grow >= off[i]) ? i : e;
  float su = stats[grow * 2 + 0], sq = stats[grow * 2 + 1];
  float mu = su * (1.f / 4096.f);
  float var = sq * (1.f / 4096.f) - mu * mu;
  float rs = rsqrtf(var + 1e-5f);
  size_t hoff = (size_t)rl * Hh + c8;
  ushort4 hv0 = ((ushort4*)(h + hoff))[0];
  ushort4 hv1 = ((ushort4*)(h + hoff))[1];
  float4 g0  = ((const float4*)(lng + (size_t)e * Hh + c8))[0];
  float4 g1  = ((const float4*)(lng + (size_t)e * Hh + c8))[1];
  float4 b0  = ((const float4*)(lnb + (size_t)e * Hh + c8))[0];
  float4 b1v = ((const float4*)(lnb + (size_t)e * Hh + c8))[1];
  float xv[8] = {bf2f(hv0.x), bf2f(hv0.y), bf2f(hv0.z), bf2f(hv0.w),
                 bf2f(hv1.x), bf2f(hv1.y), bf2f(hv1.z), bf2f(hv1.w)};
  float gg[8] = {g0.x, g0.y, g0.z, g0.w, g1.x, g1.y, g1.z, g1.w};
  float bb[8] = {b0.x, b0.y, b0.z, b0.w, b1v.x, b1v.y, b1v.z, b1v.w};
  ushort o[8];
  #pragma unroll
  for (int i = 0; i < 8; i++){
    float v = (xv[i] - mu) * rs * gg[i] + bb[i];
    float y = 0.5f * v * (1.f + erff(v * 0.70710678118654752f));
    o[i] = f2bf(y);
  }
  ushort4 o0 = {o[0], o[1], o[2], o[3]}, o1 = {o[4], o[5], o[6], o[7]};
  ((ushort4*)(h + hoff))[0] = o0;
  ((ushort4*)(h + hoff))[1] = o1;
}

// ---------------- host launch ----------------
extern "C" void kernel_launch(void* const* d_in, const int* in_sizes, int n_in,
                              void* d_out, int out_size, void* d_ws, size_t ws_size,
                              hipStream_t stream)
{
  const float* x   = (const float*)d_in[0];
  const float* gw  = (const float*)d_in[1];
  const float* gb  = (const float*)d_in[2];
  const float* w1  = (const float*)d_in[3];
  const float* b1  = (const float*)d_in[4];
  const float* lng = (const float*)d_in[5];
  const float* lnb = (const float*)d_in[6];
  const float* w2  = (const float*)d_in[7];
  const float* b2  = (const float*)d_in[8];
  float* outp   = (float*)d_out;
  float* logits = outp + (size_t)Bt * Cc;

  char* p = (char*)d_ws;
  auto alloc = [&](size_t bytes) -> char* {
    char* q = p; p += (bytes + 255) & ~(size_t)255; return q;
  };
  int*    ctrl  = (int*)alloc(256);            // cnt[8] | fill[8] | off[9]
  int*    cnt = ctrl; int* fill = ctrl + 8; int* off = ctrl + 16;
  int2*   topi  = (int2*)alloc((size_t)Bt * 8);
  float2* topp  = (float2*)alloc((size_t)Bt * 8);
  int*    ptok  = (int*)alloc((size_t)PCAP * 4);
  float*  pgate = (float*)alloc((size_t)PCAP * 4);
  float*  stats = (float*)alloc((size_t)PCAP * 8);
  ushort* xb    = (ushort*)alloc((size_t)Bt * Dd * 2);
  ushort* w1t   = (ushort*)alloc((size_t)Ee * Hh * Dd * 2);
  ushort* w2t   = (ushort*)alloc((size_t)Ee * Cc * Hh * 2);
  size_t used  = (size_t)(p - (char*)d_ws);
  size_t avail = ws_size > used ? ws_size - used : 0;
  long long chr = (long long)(avail / ((size_t)Hh * 2));
  chr &= ~127LL;
  int CH = (int)(chr < 128 ? 128 : (chr > PCAP ? (long long)PCAP : chr));
  ushort* hbuf = (ushort*)p;   // CH x Hh bf16

  hipMemsetAsync(d_out, 0, (size_t)Bt * Cc * 4, stream);   // logits fully overwritten by router
  hipMemsetAsync(ctrl, 0, 256, stream);
  hipMemsetAsync(ptok, 0, (size_t)PCAP * 4, stream);
  hipMemsetAsync(pgate, 0, (size_t)PCAP * 4, stream);
  hipMemsetAsync(stats, 0, (size_t)PCAP * 8, stream);

  k_router<<<Bt / 4, 256, 0, stream>>>(x, gw, gb, logits, topi, topp, cnt);
  k_offsets<<<1, 64, 0, stream>>>(cnt, off);
  k_scatter<<<Bt / 256, 256, 0, stream>>>(topi, topp, off, fill, ptok, pgate);
  k_cvt_bf16<<<(Bt * Dd / 4) / 256, 256, 0, stream>>>(x, xb, Bt * Dd / 4);
  k_transpose_bf16<<<dim3(Hh / 64, Dd / 64, Ee), 256, 0, stream>>>(w1, w1t, Dd, Hh);
  k_transpose_bf16<<<dim3(Cc / 64, Hh / 64, Ee), 256, 0, stream>>>(w2, w2t, Hh, Cc);

  for (int base = 0; base < PCAP; base += CH){
    int rows = (PCAP - base < CH) ? (PCAP - base) : CH;
    dim3 g1(rows / 128, Hh / 128);
    k_gemm<0, Dd, Hh><<<g1, 256, 0, stream>>>(xb, w1t, b1, off, ptok, pgate, stats, hbuf, nullptr, base);
    k_lngelu<<<rows * 2, 256, 0, stream>>>(hbuf, stats, off, lng, lnb, base);
    dim3 g2(rows / 128, Cc / 128);
    k_gemm<1, Hh, Cc><<<g2, 256, 0, stream>>>(hbuf, w2t, b2, off, ptok, pgate, nullptr, nullptr, outp, base);
  }
}